// Round 5
// baseline (194.420 us; speedup 1.0000x reference)
//
#include <hip/hip_runtime.h>

// Per-sample depthwise 7x7 cross-correlation, NHWC, SAME padding.
// inputs:  [B,H,W,C] fp32, kernels: [B,7,7,C] fp32, out: [B,H,W,C] fp32.
// out[b,y,x,c] = sum_{i,j} in[b, y+i-3, x+j-3, c] * ker[b,i,j,c]  (zero pad)
//
// Weights in LDS ([c][52], b128-aligned, 13c mod 8 bijective -> conflict-free
// quad reads). Ping-pong tap prefetch hides global-load latency under the
// 196-FMA weight pass. x0/xg readfirstlane'd -> scalar addressing.

#define BB 32
#define HH 128
#define WW 128
#define CC 128
#define KH 7
#define KW 7

#define XPT 4                        // x outputs per thread
#define NTAP (XPT + KW - 1)          // 10 input columns per row per thread
#define XG 4                         // x-groups per block (512 threads / 128 c)
#define SLABW (XG * XPT)             // 16 output columns per block
#define NXS (WW / SLABW)             // 8 x-slabs
#define YSPLIT 4
#define YROWS (HH / YSPLIT)          // 32 output rows per block
#define GRID (BB * NXS * YSPLIT)     // 1024 blocks = 4 per CU
#define WSTRIDE 52                   // per-c weight stride (floats), 16B-aligned

__global__ __launch_bounds__(512) void crossconv_kernel(
    const float* __restrict__ in,
    const float* __restrict__ ker,
    float* __restrict__ out)
{
    __shared__ float lds_w[CC * WSTRIDE];   // 26624 B

    const int tid = threadIdx.x;
    const int c  = tid & (CC - 1);   // lanes contiguous in c -> coalesced
    // tid>>7 is constant within a 64-lane wave -> safe to scalarize.
    const int xg = __builtin_amdgcn_readfirstlane(tid >> 7);   // 0..3

    // Bijective XCD swizzle (GRID=1024, 128 blocks/XCD = 4 whole samples):
    // halo + weight sharing stays within one XCD's L2.
    const int bid = blockIdx.x;
    const int swz = (bid & 7) * (GRID / 8) + (bid >> 3);
    const int b  = swz >> 5;         // 32 blocks per sample
    const int xs = (swz >> 2) & 7;
    const int yh = swz & 3;
    const int x0 = xs * SLABW + xg * XPT;  // wave-uniform (scalar)
    const int y0 = yh * YROWS;

    // Stage this sample's weights into LDS, transposed to [c][f].
    {
        const float* kb = ker + ((size_t)b * KH * KW) * CC + c;
        for (int f = xg; f < KH * KW; f += XG)
            lds_w[c * WSTRIDE + f] = kb[f * CC];
    }
    __syncthreads();

    const float* ib = in  + ((size_t)b * HH * WW) * CC;
    float*       ob = out + ((size_t)b * HH * WW) * CC;
    const float* wp = &lds_w[c * WSTRIDE];

    // Taps cover columns x0-3 .. x0+XPT+2; wave-uniform edge test.
    const bool interior = (x0 >= 3) && (x0 + XPT + 2 < WW);

    // Sliding accumulator ring: acc[s][xo] is partial for output row y = yi-3+s.
    float acc[KH][XPT];
    #pragma unroll
    for (int s = 0; s < KH; ++s)
        #pragma unroll
        for (int xo = 0; xo < XPT; ++xo) acc[s][xo] = 0.0f;

    auto load_taps = [&](float* t, int yi) {
        if (yi < 0 || yi >= HH) {
            #pragma unroll
            for (int j = 0; j < NTAP; ++j) t[j] = 0.0f;
            return;
        }
        const float* row = ib + (size_t)yi * WW * CC + c;  // per-lane part: c only
        if (interior) {
            #pragma unroll
            for (int j = 0; j < NTAP; ++j)
                t[j] = row[(x0 - 3 + j) * CC];             // scalar offsets
        } else {
            #pragma unroll
            for (int j = 0; j < NTAP; ++j) {
                const int xx = x0 - 3 + j;
                t[j] = (xx >= 0 && xx < WW) ? row[xx * CC] : 0.0f;
            }
        }
    };

    // One weight pass: stream 13 b128 quads from LDS, 196 FMAs on taps t,
    // write completed output row y = yi-3, shift ring.
    auto wpass = [&](const float* t, int yi) {
        // Compiler barrier: keep the per-pass LDS weight reads in the loop
        // (hoisting them would need 49 registers -> spill).
        asm volatile("" ::: "memory");
        #pragma unroll
        for (int k = 0; k < 12; ++k) {
            const float4 q = *(const float4*)(wp + k * 4);
            #pragma unroll
            for (int m = 0; m < 4; ++m) {
                const int f = k * 4 + m;
                const int i = f / KW, j = f % KW;
                const float wv = (&q.x)[m];
                #pragma unroll
                for (int xo = 0; xo < XPT; ++xo)
                    acc[6 - i][xo] = fmaf(wv, t[xo + j], acc[6 - i][xo]);
            }
        }
        {   // f = 48 (i=6, j=6) read as b128 (pad lanes unused) -> conflict-free
            const float4 q = *(const float4*)(wp + 48);
            #pragma unroll
            for (int xo = 0; xo < XPT; ++xo)
                acc[0][xo] = fmaf(q.x, t[xo + 6], acc[0][xo]);
        }

        const int y = yi - 3;
        if (y >= y0) {
            float* orow = ob + ((size_t)y * WW + x0) * CC + c;
            #pragma unroll
            for (int xo = 0; xo < XPT; ++xo)
                orow[xo * CC] = acc[0][xo];
        }

        #pragma unroll
        for (int s = 0; s < KH - 1; ++s)
            #pragma unroll
            for (int xo = 0; xo < XPT; ++xo) acc[s][xo] = acc[s + 1][xo];
        #pragma unroll
        for (int xo = 0; xo < XPT; ++xo) acc[KH - 1][xo] = 0.0f;
    };

    const int yi0 = y0 - 3;
    const int yi1 = y0 + YROWS + 2;  // 38 input rows -> 19 ping-pong pairs

    float t[NTAP], tn[NTAP];
    load_taps(t, yi0);

    #pragma unroll 1
    for (int yi = yi0; yi <= yi1; yi += 2) {
        load_taps(tn, yi + 1);           // issue loads; latency hides under pass
        wpass(t, yi);
        load_taps(t, (yi + 2 <= yi1) ? (yi + 2) : -1);
        wpass(tn, yi + 1);
    }
}

extern "C" void kernel_launch(void* const* d_in, const int* in_sizes, int n_in,
                              void* d_out, int out_size, void* d_ws, size_t ws_size,
                              hipStream_t stream) {
    const float* in  = (const float*)d_in[0];
    const float* ker = (const float*)d_in[1];
    float*       out = (float*)d_out;

    crossconv_kernel<<<GRID, 512, 0, stream>>>(in, ker, out);
}